// Round 6
// baseline (62.439 us; speedup 1.0000x reference)
//
#include <hip/hip_runtime.h>
#include <hip/hip_bf16.h>

#define BDIM 512

typedef __attribute__((ext_vector_type(8))) _Float16 f16x8;
typedef __attribute__((ext_vector_type(4))) _Float16 f16x4;
typedef __attribute__((ext_vector_type(4))) float f32x4;

// RoPE cos/sin table: tab[t*32+u] = (cos(t*invf_u), sin(t*invf_u)), t in [0,256), u in [0,32).
__global__ void rope_tab_kernel(float2* __restrict__ tab) {
    int idx = blockIdx.x * 256 + threadIdx.x;      // 8192 entries
    int t = idx >> 5, u = idx & 31;
    float inv = __expf((float)u * -0.28782313662425572f);  // 10000^(-u/32)
    float sn, cs;
    sincosf((float)t * inv, &sn, &cs);
    tab[idx] = make_float2(cs, sn);
}

// Local windowed attention with RoPE. b=32, n=4096, d=64, WINDOW=128, 1 backward window.
// One block per (batch, window). 512 threads = 8 waves; wave wv owns q-rows [16wv,16wv+16).
// FLASH-SPLIT: K/V staged in TWO 128-row halves (LDS 35.8KB -> 4 blocks/CU), QK^T in
// 64-col chunks (acc[4] live) with online softmax.
// LAYOUT DISCIPLINE (R5 bug): after swapped QK^T, per-query stats (m, s, alpha) are in
// the c-layout (query = lane&15); accO is in the row-layout (query = 4g+r). Every
// per-query factor applied to accO MUST be shuffled c-layout -> row-layout first.
template<bool USE_TAB>
__global__ __launch_bounds__(512, 6)
void la_kernel(const float* __restrict__ qg, const float* __restrict__ kg,
               const float* __restrict__ vg, float* __restrict__ outg,
               const float2* __restrict__ tab)
{
    __shared__ _Float16 Ks[128][72];   // 18432 B
    __shared__ _Float16 Vt[64][136];   // 17408 B

    const int ww = blockIdx.x, bb = blockIdx.y;
    const int tid = threadIdx.x;
    const size_t qbase = ((size_t)bb * 4096 + (size_t)ww * 128) * 64;
    const int srow0 = ww * 128 - 128;              // first K/V source row of half 0
    const float NEG = -3.0e38f;
    const float NLT32 = -0.28782313662425572f;

    const int wv = tid >> 6, lane = tid & 63, g = lane >> 4, c = lane & 15;
    const int qrow = wv * 16 + c;

    // ---- per-lane Q load + RoPE (t = 128 + qrow) ----
    f16x8 qa0, qa1;
    {
        const float* p = qg + qbase + (size_t)qrow * 64 + 8 * g;
        float4 a0 = *(const float4*)p;
        float4 a1 = *(const float4*)(p + 4);
        float4 b0 = *(const float4*)(p + 32);
        float4 b1 = *(const float4*)(p + 36);
        float ra[8] = {a0.x,a0.y,a0.z,a0.w,a1.x,a1.y,a1.z,a1.w};
        float rb[8] = {b0.x,b0.y,b0.z,b0.w,b1.x,b1.y,b1.z,b1.w};
        float tq = (float)(128 + qrow);
        #pragma unroll
        for (int u = 0; u < 8; ++u) {
            float sn, cs;
            if (USE_TAB) {
                float2 t2 = tab[(128 + qrow) * 32 + 8 * g + u];
                cs = t2.x; sn = t2.y;
            } else {
                float invf = __expf((float)(8 * g + u) * NLT32);
                __sincosf(tq * invf, &sn, &cs);
            }
            float a = ra[u] * 0.125f, b = rb[u] * 0.125f;
            qa0[u] = (_Float16)(a * cs - b * sn);
            qa1[u] = (_Float16)(b * cs + a * sn);
        }
    }

    // ---- flash state (m, s in c-layout; accO in row-layout) ----
    f32x4 accO[4];
    #pragma unroll
    for (int nt = 0; nt < 4; ++nt) accO[nt] = (f32x4){0.f,0.f,0.f,0.f};
    float m = NEG, s = 0.f;

    #pragma unroll
    for (int h = 0; h < 2; ++h) {
        if (h == 0 && ww == 0) continue;           // half 0 of window 0 is all padding

        // ---- stage K half (RoPE, t = 128h + j), b64 LDS writes ----
        #pragma unroll
        for (int it = 0; it < 2; ++it) {
            int task = tid + it * 512;             // 1024 tasks: 128 rows x 8 col-blocks
            int j = task >> 3, cb = (task & 7) << 2;
            int tj = 128 * h + j;                  // RoPE position; also source offset
            const float* p = kg + ((size_t)bb * 4096 + srow0 + tj) * 64 + cb;
            float4 x1 = *(const float4*)p;
            float4 x2 = *(const float4*)(p + 32);
            const float* x1p = &x1.x;
            const float* x2p = &x2.x;
            f16x4 lo, hi;
            #pragma unroll
            for (int u = 0; u < 4; ++u) {
                float sn, cs;
                if (USE_TAB) {
                    float2 t2 = tab[tj * 32 + cb + u];
                    cs = t2.x; sn = t2.y;
                } else {
                    float invf = __expf((float)(cb + u) * NLT32);
                    __sincosf((float)tj * invf, &sn, &cs);
                }
                lo[u] = (_Float16)(x1p[u] * cs - x2p[u] * sn);
                hi[u] = (_Float16)(x2p[u] * cs + x1p[u] * sn);
            }
            *(f16x4*)&Ks[j][cb]      = lo;
            *(f16x4*)&Ks[j][cb + 32] = hi;
        }

        // ---- stage V half transposed ----
        #pragma unroll
        for (int it = 0; it < 4; ++it) {
            int task = tid + it * 512;             // 2048 tasks: 128 rows x 16 float4
            int j = task >> 4, eq = task & 15;
            float4 x = *(const float4*)(vg + ((size_t)bb * 4096 + srow0 + 128 * h + j) * 64 + 4 * eq);
            Vt[4 * eq + 0][j] = (_Float16)x.x;
            Vt[4 * eq + 1][j] = (_Float16)x.y;
            Vt[4 * eq + 2][j] = (_Float16)x.z;
            Vt[4 * eq + 3][j] = (_Float16)x.w;
        }

        __syncthreads();

        // ---- two 64-col chunks: QK^T -> online softmax -> PV ----
        #pragma unroll
        for (int ch = 0; ch < 2; ++ch) {
            f32x4 acc[4];
            #pragma unroll
            for (int jt = 0; jt < 4; ++jt) acc[jt] = (f32x4){0.f,0.f,0.f,0.f};

            #pragma unroll
            for (int jt = 0; jt < 4; ++jt) {
                int row = ch * 64 + jt * 16 + c;
                f16x8 kb0 = *(const f16x8*)&Ks[row][8 * g];
                f16x8 kb1 = *(const f16x8*)&Ks[row][32 + 8 * g];
                acc[jt] = __builtin_amdgcn_mfma_f32_16x16x32_f16(kb0, qa0, acc[jt], 0, 0, 0);
                acc[jt] = __builtin_amdgcn_mfma_f32_16x16x32_f16(kb1, qa1, acc[jt], 0, 0, 0);
            }

            // causal mask only in half 1: j = 128 + j'' masked when j'' > qrow
            if (h == 1) {
                #pragma unroll
                for (int jt = 0; jt < 4; ++jt)
                    #pragma unroll
                    for (int r = 0; r < 4; ++r) {
                        int jj = ch * 64 + jt * 16 + 4 * g + r;
                        if (jj > qrow) acc[jt][r] = NEG;
                    }
            }

            // chunk max (c-layout: this lane's 16 slots + across the 4 k-groups)
            float mx = NEG;
            #pragma unroll
            for (int jt = 0; jt < 4; ++jt)
                #pragma unroll
                for (int r = 0; r < 4; ++r) mx = fmaxf(mx, acc[jt][r]);
            mx = fmaxf(mx, __shfl_xor(mx, 16));
            mx = fmaxf(mx, __shfl_xor(mx, 32));

            float mnew = fmaxf(m, mx);
            float alpha = __expf(m - mnew);        // first real chunk: exp(-3e38-x) = 0

            float ps = 0.f;
            f16x8 pa[2];
            #pragma unroll
            for (int jt = 0; jt < 4; ++jt)
                #pragma unroll
                for (int r = 0; r < 4; ++r) {
                    float p = __expf(acc[jt][r] - mnew);   // masked -> underflows to 0
                    ps += p;
                    pa[jt >> 1][(jt & 1) * 4 + r] = (_Float16)p;
                }
            ps += __shfl_xor(ps, 16);
            ps += __shfl_xor(ps, 32);

            s = s * alpha + ps;
            m = mnew;

            // R5 FIX: alpha is per-query in c-layout; accO rows are query 4g+r.
            // Shuffle alpha into the row-layout before rescaling.
            float alphaD[4];
            #pragma unroll
            for (int r = 0; r < 4; ++r)
                alphaD[r] = __shfl(alpha, (lane & 48) | (4 * g + r));
            #pragma unroll
            for (int nt = 0; nt < 4; ++nt)
                #pragma unroll
                for (int r = 0; r < 4; ++r) accO[nt][r] *= alphaD[r];

            // PV for this chunk: 2 k-steps of 32 j-slots
            #pragma unroll
            for (int st = 0; st < 2; ++st) {
                #pragma unroll
                for (int nt = 0; nt < 4; ++nt) {
                    f16x4 vb0 = *(const f16x4*)&Vt[nt * 16 + c][ch * 64 + st * 32 + 4 * g];
                    f16x4 vb1 = *(const f16x4*)&Vt[nt * 16 + c][ch * 64 + st * 32 + 16 + 4 * g];
                    f16x8 vb;
                    #pragma unroll
                    for (int u = 0; u < 4; ++u) { vb[u] = vb0[u]; vb[u + 4] = vb1[u]; }
                    accO[nt] = __builtin_amdgcn_mfma_f32_16x16x32_f16(pa[st], vb, accO[nt], 0, 0, 0);
                }
            }
        }

        if (h == 0) __syncthreads();               // before half 1 overwrites the buffers
    }

    // ---- epilogue: 1/s (c-layout) -> row-layout, then store ----
    float rcp = 1.0f / s;
    float rcpD[4];
    #pragma unroll
    for (int r = 0; r < 4; ++r)
        rcpD[r] = __shfl(rcp, (lane & 48) | (4 * g + r));

    float* op = outg + qbase + (size_t)(wv * 16) * 64;
    #pragma unroll
    for (int nt = 0; nt < 4; ++nt)
        #pragma unroll
        for (int r = 0; r < 4; ++r)
            op[(size_t)(4 * g + r) * 64 + nt * 16 + c] = accO[nt][r] * rcpD[r];
}

extern "C" void kernel_launch(void* const* d_in, const int* in_sizes, int n_in,
                              void* d_out, int out_size, void* d_ws, size_t ws_size,
                              hipStream_t stream) {
    (void)in_sizes; (void)n_in; (void)out_size;
    const float* q = (const float*)d_in[0];
    const float* k = (const float*)d_in[1];
    const float* v = (const float*)d_in[2];
    float* out = (float*)d_out;
    dim3 grid(32, 32);  // x = window, y = batch

    if (ws_size >= 8192 * sizeof(float2)) {
        float2* tab = (float2*)d_ws;
        rope_tab_kernel<<<32, 256, 0, stream>>>(tab);
        la_kernel<true><<<grid, BDIM, 0, stream>>>(q, k, v, out, tab);
    } else {
        la_kernel<false><<<grid, BDIM, 0, stream>>>(q, k, v, out, nullptr);
    }
}

// Round 7
// 49.003 us; speedup vs baseline: 1.2742x; 1.2742x over previous
//
#include <hip/hip_runtime.h>
#include <hip/hip_bf16.h>

#define BDIM 512

typedef __attribute__((ext_vector_type(8))) _Float16 f16x8;
typedef __attribute__((ext_vector_type(4))) _Float16 f16x4;
typedef __attribute__((ext_vector_type(4))) float f32x4;

// RoPE cos/sin table: tab[t*32+u] = (cos(t*invf_u), sin(t*invf_u)), t in [0,256), u in [0,32).
__global__ void rope_tab_kernel(float2* __restrict__ tab) {
    int idx = blockIdx.x * 256 + threadIdx.x;      // 8192 entries
    int t = idx >> 5, u = idx & 31;
    float inv = __expf((float)u * -0.28782313662425572f);  // 10000^(-u/32)
    float sn, cs;
    sincosf((float)t * inv, &sn, &cs);
    tab[idx] = make_float2(cs, sn);
}

// Local windowed attention with RoPE. b=32, n=4096, d=64, WINDOW=128, 1 backward window.
// EXACT R2 structure (44.7us, zero spill: WRITE == output bytes) + RoPE table ONLY.
// R3/R4/R6 lesson: every occupancy-buying change (reg-held V, skip branches in MFMA
// loops, launch_bounds(512,6) + unrolled flash loop) made the allocator spill to
// scratch -> 8-66MB of extra HBM writes, net regression. Keep the allocator happy.
// QK^T swapped: D = mfma(K,Q) -> lane holds P[i = wv*16 + (lane&15)][j-slots];
// softmax via shfl_xor(16,32); P feeds PV from registers; V read with the SAME
// j-slot permutation (dot products invariant under shared k-relabeling).
template<bool USE_TAB>
__global__ __launch_bounds__(512, 4)
void la_kernel(const float* __restrict__ qg, const float* __restrict__ kg,
               const float* __restrict__ vg, float* __restrict__ outg,
               const float2* __restrict__ tab)
{
    __shared__ _Float16 Ks[256][72];   // stride 144B -> 2-way bank alias (free)
    __shared__ _Float16 Vt[64][268];   // stride 536B; 8B-aligned rows for b64

    const int ww = blockIdx.x, bb = blockIdx.y;
    const int tid = threadIdx.x;
    const bool w0 = (ww == 0);
    const size_t qbase = ((size_t)bb * 4096 + (size_t)ww * 128) * 64;
    const float NEG = -3.0e38f;
    const float NLT32 = -0.28782313662425572f;
    const int srow0 = ww * 128 - 128;

    const int wv = tid >> 6, lane = tid & 63, g = lane >> 4, c = lane & 15;
    const int qrow = wv * 16 + c;

    // ---- per-lane Q load + RoPE (t = 128 + qrow) ----
    f16x8 qa0, qa1;
    {
        const float* p = qg + qbase + (size_t)qrow * 64 + 8 * g;
        float4 a0 = *(const float4*)p;
        float4 a1 = *(const float4*)(p + 4);
        float4 b0 = *(const float4*)(p + 32);
        float4 b1 = *(const float4*)(p + 36);
        float ra[8] = {a0.x,a0.y,a0.z,a0.w,a1.x,a1.y,a1.z,a1.w};
        float rb[8] = {b0.x,b0.y,b0.z,b0.w,b1.x,b1.y,b1.z,b1.w};
        float tq = (float)(128 + qrow);
        #pragma unroll
        for (int u = 0; u < 8; ++u) {
            float sn, cs;
            if (USE_TAB) {
                float2 t2 = tab[(128 + qrow) * 32 + 8 * g + u];
                cs = t2.x; sn = t2.y;
            } else {
                float invf = __expf((float)(8 * g + u) * NLT32);
                __sincosf(tq * invf, &sn, &cs);
            }
            float a = ra[u] * 0.125f, b = rb[u] * 0.125f;
            qa0[u] = (_Float16)(a * cs - b * sn);
            qa1[u] = (_Float16)(b * cs + a * sn);
        }
    }

    // ---- K staging with RoPE (t = j) ----
    for (int task = tid; task < 2048; task += BDIM) {
        int j  = task >> 3;
        int cb = (task & 7) << 2;
        int src = srow0 + j;
        float4 x1 = {0.f,0.f,0.f,0.f}, x2 = {0.f,0.f,0.f,0.f};
        if (src >= 0) {
            const float* p = kg + ((size_t)bb * 4096 + src) * 64 + cb;
            x1 = *(const float4*)p;
            x2 = *(const float4*)(p + 32);
        }
        const float* x1p = &x1.x;
        const float* x2p = &x2.x;
        f16x4 lo, hi;
        #pragma unroll
        for (int u = 0; u < 4; ++u) {
            float sn, cs;
            if (USE_TAB) {
                float2 t2 = tab[j * 32 + cb + u];
                cs = t2.x; sn = t2.y;
            } else {
                float invf = __expf((float)(cb + u) * NLT32);
                __sincosf((float)j * invf, &sn, &cs);
            }
            lo[u] = (_Float16)(x1p[u] * cs - x2p[u] * sn);
            hi[u] = (_Float16)(x2p[u] * cs + x1p[u] * sn);
        }
        *(f16x4*)&Ks[j][cb]      = lo;
        *(f16x4*)&Ks[j][cb + 32] = hi;
    }

    // ---- V staging (transposed; pad rows -> 0, their weight is exactly 0) ----
    for (int task = tid; task < 4096; task += BDIM) {
        int j  = task >> 4;
        int cb = (task & 15) << 2;
        int src = srow0 + j;
        float4 x = {0.f,0.f,0.f,0.f};
        if (src >= 0)
            x = *(const float4*)(vg + ((size_t)bb * 4096 + src) * 64 + cb);
        const float* xp = &x.x;
        #pragma unroll
        for (int u = 0; u < 4; ++u)
            Vt[cb + u][j] = (_Float16)xp[u];
    }

    __syncthreads();

    // ---- QK^T (swapped): acc[jt] holds D[j = 16jt+4g+r][i = c] ----
    f32x4 acc[16];
    #pragma unroll
    for (int jt = 0; jt < 16; ++jt) acc[jt] = (f32x4){0.f,0.f,0.f,0.f};

    #pragma unroll
    for (int jt = 0; jt < 16; ++jt) {
        f16x8 kb0 = *(const f16x8*)&Ks[jt * 16 + c][8 * g];
        f16x8 kb1 = *(const f16x8*)&Ks[jt * 16 + c][32 + 8 * g];
        acc[jt] = __builtin_amdgcn_mfma_f32_16x16x32_f16(kb0, qa0, acc[jt], 0, 0, 0);
        acc[jt] = __builtin_amdgcn_mfma_f32_16x16x32_f16(kb1, qa1, acc[jt], 0, 0, 0);
    }

    // ---- mask + softmax over j for row i = qrow ----
    #pragma unroll
    for (int jt = 0; jt < 16; ++jt) {
        #pragma unroll
        for (int r = 0; r < 4; ++r) {
            int j = jt * 16 + 4 * g + r;
            if ((j > qrow + 128) || (w0 && j < 128)) acc[jt][r] = NEG;
        }
    }

    float m = NEG;
    #pragma unroll
    for (int jt = 0; jt < 16; ++jt)
        #pragma unroll
        for (int r = 0; r < 4; ++r) m = fmaxf(m, acc[jt][r]);
    m = fmaxf(m, __shfl_xor(m, 16));
    m = fmaxf(m, __shfl_xor(m, 32));

    float s = 0.f;
    #pragma unroll
    for (int jt = 0; jt < 16; ++jt) {
        #pragma unroll
        for (int r = 0; r < 4; ++r) {
            float p = __expf(acc[jt][r] - m);      // masked -> underflows to 0
            acc[jt][r] = p;
            s += p;
        }
    }
    s += __shfl_xor(s, 16);
    s += __shfl_xor(s, 32);
    float rcp = 1.0f / s;

    // P -> f16 A-fragments
    f16x8 pa[8];
    #pragma unroll
    for (int s8 = 0; s8 < 8; ++s8)
        #pragma unroll
        for (int r = 0; r < 4; ++r) {
            pa[s8][r]     = (_Float16)(acc[2 * s8][r] * rcp);
            pa[s8][r + 4] = (_Float16)(acc[2 * s8 + 1][r] * rcp);
        }

    // ---- PV: A = P (regs), B = V with the SAME j-slot permutation ----
    f32x4 accO[4];
    #pragma unroll
    for (int nt = 0; nt < 4; ++nt) accO[nt] = (f32x4){0.f,0.f,0.f,0.f};

    #pragma unroll
    for (int s8 = 0; s8 < 8; ++s8) {
        #pragma unroll
        for (int nt = 0; nt < 4; ++nt) {
            f16x4 vb0 = *(const f16x4*)&Vt[nt * 16 + c][s8 * 32 + 4 * g];
            f16x4 vb1 = *(const f16x4*)&Vt[nt * 16 + c][s8 * 32 + 16 + 4 * g];
            f16x8 vb;
            #pragma unroll
            for (int u = 0; u < 4; ++u) { vb[u] = vb0[u]; vb[u + 4] = vb1[u]; }
            accO[nt] = __builtin_amdgcn_mfma_f32_16x16x32_f16(pa[s8], vb, accO[nt], 0, 0, 0);
        }
    }

    // ---- store: i = wv*16 + 4g + r, e = nt*16 + c ----
    float* op = outg + qbase + (size_t)(wv * 16) * 64;
    #pragma unroll
    for (int nt = 0; nt < 4; ++nt)
        #pragma unroll
        for (int r = 0; r < 4; ++r)
            op[(size_t)(4 * g + r) * 64 + nt * 16 + c] = accO[nt][r];
}

extern "C" void kernel_launch(void* const* d_in, const int* in_sizes, int n_in,
                              void* d_out, int out_size, void* d_ws, size_t ws_size,
                              hipStream_t stream) {
    (void)in_sizes; (void)n_in; (void)out_size;
    const float* q = (const float*)d_in[0];
    const float* k = (const float*)d_in[1];
    const float* v = (const float*)d_in[2];
    float* out = (float*)d_out;
    dim3 grid(32, 32);  // x = window, y = batch

    if (ws_size >= 8192 * sizeof(float2)) {
        float2* tab = (float2*)d_ws;
        rope_tab_kernel<<<32, 256, 0, stream>>>(tab);
        la_kernel<true><<<grid, BDIM, 0, stream>>>(q, k, v, out, tab);
    } else {
        la_kernel<false><<<grid, BDIM, 0, stream>>>(q, k, v, out, nullptr);
    }
}

// Round 8
// 37.472 us; speedup vs baseline: 1.6663x; 1.3077x over previous
//
#include <hip/hip_runtime.h>
#include <hip/hip_bf16.h>

#define BDIM 512

typedef __attribute__((ext_vector_type(8))) _Float16 f16x8;
typedef __attribute__((ext_vector_type(4))) _Float16 f16x4;
typedef __attribute__((ext_vector_type(4))) float f32x4;

// Local windowed attention with RoPE. b=32, n=4096, d=64, WINDOW=128, 1 backward window.
// One block per (batch, window). 512 threads = 8 waves; wave wv owns q-rows [16wv,16wv+16).
// FLASH-SPLIT over two 128-row K/V halves; LDS 35.5KB -> not LDS-bound; bounds (512,4)
// so the allocator never spills (R6 lesson: (512,6) forced VGPR<=85 -> 66MB spill).
// QK^T swapped: D = mfma(K,Q) -> per-query stats in c-layout (query = lane&15);
// accO in row-layout (query = 4g+r): every per-query factor shuffled c->row first.
// Vt columns PERMUTED (col = (j&96) + 8g + 4h' + r, j = (j&96) + 16h' + 4g + r) so the
// PV B-operand is a single ds_read_b128; P fragments use the same j-slot order
// (dot products invariant under a shared k-relabeling).
// Vt stride 140 f16 = 70 dw == 6 mod 32: b128 reads 2-way (free), 4-row writes 4-way.
__global__ __launch_bounds__(512, 4)
void la_kernel(const float* __restrict__ qg, const float* __restrict__ kg,
               const float* __restrict__ vg, float* __restrict__ outg)
{
    __shared__ _Float16 Ks[128][72];   // 18432 B
    __shared__ _Float16 Vt[64][140];   // 17920 B

    const int ww = blockIdx.x, bb = blockIdx.y;
    const int tid = threadIdx.x;
    const size_t qbase = ((size_t)bb * 4096 + (size_t)ww * 128) * 64;
    const int srow0 = ww * 128 - 128;              // first K/V source row of half 0
    const float NEG = -3.0e38f;
    const float NLT32 = -0.28782313662425572f;     // -ln(10000)/32

    const int wv = tid >> 6, lane = tid & 63, g = lane >> 4, c = lane & 15;
    const int qrow = wv * 16 + c;

    // ---- per-lane Q load + RoPE (t = 128 + qrow) ----
    f16x8 qa0, qa1;
    {
        const float* p = qg + qbase + (size_t)qrow * 64 + 8 * g;
        float4 a0 = *(const float4*)p;
        float4 a1 = *(const float4*)(p + 4);
        float4 b0 = *(const float4*)(p + 32);
        float4 b1 = *(const float4*)(p + 36);
        float ra[8] = {a0.x,a0.y,a0.z,a0.w,a1.x,a1.y,a1.z,a1.w};
        float rb[8] = {b0.x,b0.y,b0.z,b0.w,b1.x,b1.y,b1.z,b1.w};
        float tq = (float)(128 + qrow);
        #pragma unroll
        for (int u = 0; u < 8; ++u) {
            float invf = __expf((float)(8 * g + u) * NLT32);
            float sn, cs; __sincosf(tq * invf, &sn, &cs);
            float a = ra[u] * 0.125f, b = rb[u] * 0.125f;
            qa0[u] = (_Float16)(a * cs - b * sn);
            qa1[u] = (_Float16)(b * cs + a * sn);
        }
    }

    // ---- flash state (m, s in c-layout; accO in row-layout) ----
    f32x4 accO[4];
    #pragma unroll
    for (int nt = 0; nt < 4; ++nt) accO[nt] = (f32x4){0.f,0.f,0.f,0.f};
    float m = NEG, s = 0.f;

    #pragma unroll 1
    for (int h = 0; h < 2; ++h) {
        if (h == 0 && ww == 0) continue;           // half 0 of window 0 is all padding
        if (h == 1) __syncthreads();               // protect LDS before overwrite

        // ---- stage K half (RoPE, t = 128h + j), 2x b64 LDS writes ----
        #pragma unroll
        for (int it = 0; it < 2; ++it) {
            int task = tid + it * 512;             // 1024 tasks: 128 rows x 8 col-blocks
            int j = task >> 3, cb = (task & 7) << 2;
            int tj = 128 * h + j;                  // RoPE position; also source offset
            const float* p = kg + ((size_t)bb * 4096 + srow0 + tj) * 64 + cb;
            float4 x1 = *(const float4*)p;
            float4 x2 = *(const float4*)(p + 32);
            const float* x1p = &x1.x;
            const float* x2p = &x2.x;
            f16x4 lo, hi;
            #pragma unroll
            for (int u = 0; u < 4; ++u) {
                float invf = __expf((float)(cb + u) * NLT32);
                float sn, cs; __sincosf((float)tj * invf, &sn, &cs);
                lo[u] = (_Float16)(x1p[u] * cs - x2p[u] * sn);
                hi[u] = (_Float16)(x2p[u] * cs + x1p[u] * sn);
            }
            *(f16x4*)&Ks[j][cb]      = lo;
            *(f16x4*)&Ks[j][cb + 32] = hi;
        }

        // ---- stage V half: 4x4 transpose blocks into permuted columns ----
        {
            int jq = tid >> 4, eq = tid & 15;      // jq: 4-row group [0,32), eq: float4 col
            int colb = ((jq & 24) << 2) + 8 * (jq & 3) + 4 * ((jq >> 2) & 1); // perm(4jq)
            float4 x[4];
            #pragma unroll
            for (int w = 0; w < 4; ++w)
                x[w] = *(const float4*)(vg + ((size_t)bb * 4096 + srow0 + 128 * h + 4 * jq + w) * 64 + 4 * eq);
            #pragma unroll
            for (int u = 0; u < 4; ++u) {
                f16x4 o;
                o[0] = (_Float16)((const float*)&x[0])[u];
                o[1] = (_Float16)((const float*)&x[1])[u];
                o[2] = (_Float16)((const float*)&x[2])[u];
                o[3] = (_Float16)((const float*)&x[3])[u];
                *(f16x4*)&Vt[4 * eq + u][colb] = o;
            }
        }

        __syncthreads();

        // ---- two 64-col chunks: QK^T -> online softmax -> PV ----
        #pragma unroll
        for (int ch = 0; ch < 2; ++ch) {
            f32x4 acc[4];
            #pragma unroll
            for (int jt = 0; jt < 4; ++jt) acc[jt] = (f32x4){0.f,0.f,0.f,0.f};

            #pragma unroll
            for (int jt = 0; jt < 4; ++jt) {
                int row = ch * 64 + jt * 16 + c;
                f16x8 kb0 = *(const f16x8*)&Ks[row][8 * g];
                f16x8 kb1 = *(const f16x8*)&Ks[row][32 + 8 * g];
                acc[jt] = __builtin_amdgcn_mfma_f32_16x16x32_f16(kb0, qa0, acc[jt], 0, 0, 0);
                acc[jt] = __builtin_amdgcn_mfma_f32_16x16x32_f16(kb1, qa1, acc[jt], 0, 0, 0);
            }

            // causal mask only in half 1: j_abs = 128 + jj masked when jj > qrow
            if (h == 1) {
                #pragma unroll
                for (int jt = 0; jt < 4; ++jt)
                    #pragma unroll
                    for (int r = 0; r < 4; ++r) {
                        int jj = ch * 64 + jt * 16 + 4 * g + r;
                        if (jj > qrow) acc[jt][r] = NEG;
                    }
            }

            // chunk max (c-layout)
            float mx = NEG;
            #pragma unroll
            for (int jt = 0; jt < 4; ++jt)
                #pragma unroll
                for (int r = 0; r < 4; ++r) mx = fmaxf(mx, acc[jt][r]);
            mx = fmaxf(mx, __shfl_xor(mx, 16));
            mx = fmaxf(mx, __shfl_xor(mx, 32));

            float mnew = fmaxf(m, mx);
            float alpha = __expf(m - mnew);        // first real chunk: exp(-3e38) = 0

            float ps = 0.f;
            f16x8 pa[2];
            #pragma unroll
            for (int jt = 0; jt < 4; ++jt)
                #pragma unroll
                for (int r = 0; r < 4; ++r) {
                    float p = __expf(acc[jt][r] - mnew);   // masked -> underflows to 0
                    ps += p;
                    pa[jt >> 1][(jt & 1) * 4 + r] = (_Float16)p;
                }
            ps += __shfl_xor(ps, 16);
            ps += __shfl_xor(ps, 32);

            s = s * alpha + ps;
            m = mnew;

            // alpha (c-layout) -> row-layout before rescaling accO
            float alphaD[4];
            #pragma unroll
            for (int r = 0; r < 4; ++r)
                alphaD[r] = __shfl(alpha, (lane & 48) | (4 * g + r));
            #pragma unroll
            for (int nt = 0; nt < 4; ++nt)
                #pragma unroll
                for (int r = 0; r < 4; ++r) accO[nt][r] *= alphaD[r];

            // PV: B-operand is one b128 thanks to the permuted Vt columns
            #pragma unroll
            for (int st = 0; st < 2; ++st) {
                #pragma unroll
                for (int nt = 0; nt < 4; ++nt) {
                    f16x8 vb = *(const f16x8*)&Vt[nt * 16 + c][ch * 64 + st * 32 + 8 * g];
                    accO[nt] = __builtin_amdgcn_mfma_f32_16x16x32_f16(pa[st], vb, accO[nt], 0, 0, 0);
                }
            }
        }
    }

    // ---- epilogue: 1/s (c-layout) -> row-layout, then store ----
    float rcp = 1.0f / s;
    float rcpD[4];
    #pragma unroll
    for (int r = 0; r < 4; ++r)
        rcpD[r] = __shfl(rcp, (lane & 48) | (4 * g + r));

    float* op = outg + qbase + (size_t)(wv * 16) * 64;
    #pragma unroll
    for (int nt = 0; nt < 4; ++nt)
        #pragma unroll
        for (int r = 0; r < 4; ++r)
            op[(size_t)(4 * g + r) * 64 + nt * 16 + c] = accO[nt][r] * rcpD[r];
}

extern "C" void kernel_launch(void* const* d_in, const int* in_sizes, int n_in,
                              void* d_out, int out_size, void* d_ws, size_t ws_size,
                              hipStream_t stream) {
    (void)in_sizes; (void)n_in; (void)out_size; (void)d_ws; (void)ws_size;
    const float* q = (const float*)d_in[0];
    const float* k = (const float*)d_in[1];
    const float* v = (const float*)d_in[2];
    float* out = (float*)d_out;
    dim3 grid(32, 32);  // x = window, y = batch
    la_kernel<<<grid, BDIM, 0, stream>>>(q, k, v, out);
}

// Round 9
// 34.003 us; speedup vs baseline: 1.8363x; 1.1020x over previous
//
#include <hip/hip_runtime.h>
#include <hip/hip_bf16.h>

#define BDIM 512

typedef __attribute__((ext_vector_type(8))) _Float16 f16x8;
typedef __attribute__((ext_vector_type(4))) _Float16 f16x4;
typedef __attribute__((ext_vector_type(4))) float f32x4;

// Local windowed attention with RoPE. b=32, n=4096, d=64, WINDOW=128, 1 backward window.
// ONE BLOCK PER WINDOW-PAIR (2x, 2x+1): RoPE scores depend only on t_q - t_k (exact
// per-2-plane rotation invariance), so K staged with a BLOCK-COMMON origin is shared
// by both windows. 3 physical 128-row halves P0,P1,P2 staged into 2 rolling LDS slots
// (72.7KB -> 2 blocks/CU; grid 512 = exactly 2/CU). Window0 = P0+P1, window1 = P1+P2;
// causal mask becomes t_k > t_q; t in [0,384) keeps trig args in the reference's range.
// Carried from R8: swapped QK^T (stats in c-layout, accO in row-layout, shuffled
// factors), permuted Vt columns (PV B-operand = one ds_read_b128), flash-online
// softmax per window, launch_bounds(512,4) so the allocator never spills.
__global__ __launch_bounds__(512, 4)
void la_kernel(const float* __restrict__ qg, const float* __restrict__ kg,
               const float* __restrict__ vg, float* __restrict__ outg)
{
    __shared__ _Float16 Ks[2][128][72];   // 36864 B
    __shared__ _Float16 Vt[2][64][140];   // 35840 B   total 72704 B

    const int wp = blockIdx.x, bb = blockIdx.y;
    const int tid = threadIdx.x;
    const int wv = tid >> 6, lane = tid & 63, g = lane >> 4, c = lane & 15;
    const int base = 256 * wp - 128;      // phys row of t=0 (block-common origin)
    const float NEG = -3.0e38f;
    const float NLT32 = -0.28782313662425572f;   // -ln(10000)/32

    // hoisted inverse frequencies
    const int cbK = (tid & 7) << 2;
    float invfK[4];
    #pragma unroll
    for (int u = 0; u < 4; ++u) invfK[u] = __expf((float)(cbK + u) * NLT32);
    float invfQ[8];
    #pragma unroll
    for (int u = 0; u < 8; ++u) invfQ[u] = __expf((float)(8 * g + u) * NLT32);

    const int jqV = tid >> 4, eqV = tid & 15;
    const int colbV = ((jqV & 24) << 2) + 8 * (jqV & 3) + 4 * ((jqV >> 2) & 1);

    // ---- stage physical half mm (t = 128*mm + jloc) into slot mm&1 ----
    auto stage = [&](int mm) {
        int sl = mm & 1;
        #pragma unroll
        for (int it = 0; it < 2; ++it) {
            int j = (tid + it * 512) >> 3;         // 0..127
            int t = 128 * mm + j;
            const float* p = kg + ((size_t)bb * 4096 + base + t) * 64 + cbK;
            float4 x1 = *(const float4*)p;
            float4 x2 = *(const float4*)(p + 32);
            const float* x1p = &x1.x;
            const float* x2p = &x2.x;
            f16x4 lo, hi;
            #pragma unroll
            for (int u = 0; u < 4; ++u) {
                float sn, cs; __sincosf((float)t * invfK[u], &sn, &cs);
                lo[u] = (_Float16)(x1p[u] * cs - x2p[u] * sn);
                hi[u] = (_Float16)(x2p[u] * cs + x1p[u] * sn);
            }
            *(f16x4*)&Ks[sl][j][cbK]      = lo;
            *(f16x4*)&Ks[sl][j][cbK + 32] = hi;
        }
        // V: 4x4 transpose blocks into permuted columns
        float4 x[4];
        #pragma unroll
        for (int w = 0; w < 4; ++w)
            x[w] = *(const float4*)(vg + ((size_t)bb * 4096 + base + 128 * mm + 4 * jqV + w) * 64 + 4 * eqV);
        #pragma unroll
        for (int u = 0; u < 4; ++u) {
            f16x4 o;
            o[0] = (_Float16)((const float*)&x[0])[u];
            o[1] = (_Float16)((const float*)&x[1])[u];
            o[2] = (_Float16)((const float*)&x[2])[u];
            o[3] = (_Float16)((const float*)&x[3])[u];
            *(f16x4*)&Vt[sl][4 * eqV + u][colbV] = o;
        }
    };

    // ---- compute one window (wi = 0 or 1): keys = halves wi, wi+1 ----
    auto computeWin = [&](int wi) {
        const int qrow = tid < 0 ? 0 : (wv * 16 + c);     // wave-local query row
        const int tq = 128 * (wi + 1) + qrow;             // q position in block coords

        // Q load + RoPE
        f16x8 qa0, qa1;
        {
            const float* p = qg + ((size_t)bb * 4096 + base + tq) * 64 + 8 * g;
            float4 a0 = *(const float4*)p;
            float4 a1 = *(const float4*)(p + 4);
            float4 b0 = *(const float4*)(p + 32);
            float4 b1 = *(const float4*)(p + 36);
            float ra[8] = {a0.x,a0.y,a0.z,a0.w,a1.x,a1.y,a1.z,a1.w};
            float rb[8] = {b0.x,b0.y,b0.z,b0.w,b1.x,b1.y,b1.z,b1.w};
            #pragma unroll
            for (int u = 0; u < 8; ++u) {
                float sn, cs; __sincosf((float)tq * invfQ[u], &sn, &cs);
                float a = ra[u] * 0.125f, b = rb[u] * 0.125f;
                qa0[u] = (_Float16)(a * cs - b * sn);
                qa1[u] = (_Float16)(b * cs + a * sn);
            }
        }

        f32x4 accO[4];
        #pragma unroll
        for (int nt = 0; nt < 4; ++nt) accO[nt] = (f32x4){0.f,0.f,0.f,0.f};
        float m = NEG, s = 0.f;

        #pragma unroll 1
        for (int mm = wi; mm <= wi + 1; ++mm) {
            if (wp == 0 && mm == 0) continue;      // half P0 of block 0 is padding
            const int sl = mm & 1;
            const bool causal = (mm == wi + 1);

            #pragma unroll
            for (int ch = 0; ch < 2; ++ch) {
                f32x4 acc[4];
                #pragma unroll
                for (int jt = 0; jt < 4; ++jt) acc[jt] = (f32x4){0.f,0.f,0.f,0.f};

                #pragma unroll
                for (int jt = 0; jt < 4; ++jt) {
                    int row = ch * 64 + jt * 16 + c;
                    f16x8 kb0 = *(const f16x8*)&Ks[sl][row][8 * g];
                    f16x8 kb1 = *(const f16x8*)&Ks[sl][row][32 + 8 * g];
                    acc[jt] = __builtin_amdgcn_mfma_f32_16x16x32_f16(kb0, qa0, acc[jt], 0, 0, 0);
                    acc[jt] = __builtin_amdgcn_mfma_f32_16x16x32_f16(kb1, qa1, acc[jt], 0, 0, 0);
                }

                if (causal) {
                    #pragma unroll
                    for (int jt = 0; jt < 4; ++jt)
                        #pragma unroll
                        for (int r = 0; r < 4; ++r) {
                            int jj = ch * 64 + jt * 16 + 4 * g + r;
                            if (jj > qrow) acc[jt][r] = NEG;
                        }
                }

                // chunk max (c-layout)
                float mx = NEG;
                #pragma unroll
                for (int jt = 0; jt < 4; ++jt)
                    #pragma unroll
                    for (int r = 0; r < 4; ++r) mx = fmaxf(mx, acc[jt][r]);
                mx = fmaxf(mx, __shfl_xor(mx, 16));
                mx = fmaxf(mx, __shfl_xor(mx, 32));

                float mnew = fmaxf(m, mx);
                float alpha = __expf(m - mnew);

                float ps = 0.f;
                f16x8 pa[2];
                #pragma unroll
                for (int jt = 0; jt < 4; ++jt)
                    #pragma unroll
                    for (int r = 0; r < 4; ++r) {
                        float p = __expf(acc[jt][r] - mnew);
                        ps += p;
                        pa[jt >> 1][(jt & 1) * 4 + r] = (_Float16)p;
                    }
                ps += __shfl_xor(ps, 16);
                ps += __shfl_xor(ps, 32);

                s = s * alpha + ps;
                m = mnew;

                // alpha (c-layout) -> row-layout before rescaling accO
                float alphaD[4];
                #pragma unroll
                for (int r = 0; r < 4; ++r)
                    alphaD[r] = __shfl(alpha, (lane & 48) | (4 * g + r));
                #pragma unroll
                for (int nt = 0; nt < 4; ++nt)
                    #pragma unroll
                    for (int r = 0; r < 4; ++r) accO[nt][r] *= alphaD[r];

                // PV: B-operand is one b128 (permuted Vt)
                #pragma unroll
                for (int st = 0; st < 2; ++st) {
                    #pragma unroll
                    for (int nt = 0; nt < 4; ++nt) {
                        f16x8 vb = *(const f16x8*)&Vt[sl][nt * 16 + c][ch * 64 + st * 32 + 8 * g];
                        accO[nt] = __builtin_amdgcn_mfma_f32_16x16x32_f16(pa[st], vb, accO[nt], 0, 0, 0);
                    }
                }
            }
        }

        // epilogue: 1/s (c-layout) -> row-layout, store
        float rcp = 1.0f / s;
        float rcpD[4];
        #pragma unroll
        for (int r = 0; r < 4; ++r)
            rcpD[r] = __shfl(rcp, (lane & 48) | (4 * g + r));

        float* op = outg + ((size_t)bb * 4096 + base + 128 * (wi + 1) + wv * 16) * 64;
        #pragma unroll
        for (int nt = 0; nt < 4; ++nt)
            #pragma unroll
            for (int r = 0; r < 4; ++r)
                op[(size_t)(4 * g + r) * 64 + nt * 16 + c] = accO[nt][r] * rcpD[r];
    };

    // ---- schedule: stage P0,P1 -> win0 -> stage P2 (slot0) -> win1 ----
    if (wp > 0) stage(0);
    stage(1);
    __syncthreads();
    computeWin(0);
    __syncthreads();                      // all reads of slot0 done
    stage(2);
    __syncthreads();
    computeWin(1);
}

extern "C" void kernel_launch(void* const* d_in, const int* in_sizes, int n_in,
                              void* d_out, int out_size, void* d_ws, size_t ws_size,
                              hipStream_t stream) {
    (void)in_sizes; (void)n_in; (void)out_size; (void)d_ws; (void)ws_size;
    const float* q = (const float*)d_in[0];
    const float* k = (const float*)d_in[1];
    const float* v = (const float*)d_in[2];
    float* out = (float*)d_out;
    dim3 grid(16, 32);  // x = window-pair, y = batch
    la_kernel<<<grid, BDIM, 0, stream>>>(q, k, v, out);
}